// Round 6
// baseline (892.121 us; speedup 1.0000x reference)
//
#include <hip/hip_runtime.h>

// ---------------- constants ----------------
#define Bn 8
#define Sn 768
#define Hn 768
#define NHn 12
#define HDn 64
#define NLn 5

typedef unsigned short u16;
typedef __bf16 bf16x8 __attribute__((ext_vector_type(8)));
typedef short s16x8 __attribute__((ext_vector_type(8)));
typedef float f32x4 __attribute__((ext_vector_type(4)));
typedef unsigned short u16x4 __attribute__((ext_vector_type(4)));

static __device__ __forceinline__ float bf2f(u16 v) {
    return __uint_as_float(((unsigned)v) << 16);
}
static __device__ __forceinline__ u16 f2bf(float f) {
    unsigned u = __float_as_uint(f);
    unsigned r = u + 0x7fffu + ((u >> 16) & 1u);
    return (u16)(r >> 16);
}
static __device__ __forceinline__ bf16x8 ld8(const u16* p) {
    return *reinterpret_cast<const bf16x8*>(p);
}
static __device__ __forceinline__ void glds16(const u16* g, u16* l) {
    __builtin_amdgcn_global_load_lds(
        (const __attribute__((address_space(1))) void*)g,
        (__attribute__((address_space(3))) void*)l, 16, 0, 0);
}

// ---------------- f32 -> bf16 conversion ----------------
__global__ __launch_bounds__(256) void k_f2b(
    const float* __restrict__ in, u16* __restrict__ out, int n4)
{
    int i = blockIdx.x * 256 + threadIdx.x;
    if (i < n4) {
        float4 v = reinterpret_cast<const float4*>(in)[i];
        u16x4 o;
        o[0] = f2bf(v.x); o[1] = f2bf(v.y); o[2] = f2bf(v.z); o[3] = f2bf(v.w);
        reinterpret_cast<u16x4*>(out)[i] = o;
    }
}

// transpose f32 HxH -> bf16 HxH (out[i,o] = in[o,i]).  grid (12,12,count)
__global__ __launch_bounds__(256) void k_transpose(
    const float* __restrict__ in, u16* __restrict__ out)
{
    __shared__ float T[64][65];
    const float* src = in + (size_t)blockIdx.z * Hn * Hn;
    u16* dst = out + (size_t)blockIdx.z * Hn * Hn;
    int i0 = blockIdx.x * 64, o0 = blockIdx.y * 64;
    int x = threadIdx.x & 63, ys = threadIdx.x >> 6;
    for (int r = ys; r < 64; r += 4)
        T[r][x] = src[(size_t)(o0 + r) * Hn + i0 + x];
    __syncthreads();
    for (int r = ys; r < 64; r += 4)
        dst[(size_t)(i0 + r) * Hn + o0 + x] = f2bf(T[x][r]);
}

// ------- 64x128 double-buffered NT GEMM core (256 thr, 4 waves) ----------
// C[m,n] = sum_k A[m,k]*B[n,k]; bf16 in; out bf16 or f32 (+bias +addres).
__device__ __forceinline__ void gemm64x128(
    const u16* __restrict__ A, int lda,
    const u16* __restrict__ Bw, int ldb,
    const float* __restrict__ bias,
    const float* __restrict__ addres,
    u16* __restrict__ outH, float* __restrict__ outF, int ldc,
    int K, int m0, int n0)
{
    __shared__ u16 As[2][64 * 32];
    __shared__ u16 Bs[2][128 * 32];
    const int tid = threadIdx.x;
    const int lane = tid & 63, wave = tid >> 6;
    const int lrow = lane & 15, lquad = lane >> 4;

    const u16* gA = A + (size_t)(m0 + (tid >> 2)) * lda + (tid & 3) * 8;
    const int i1 = tid + 256;
    const u16* gB0 = Bw + (size_t)(n0 + (tid >> 2)) * ldb + (tid & 3) * 8;
    const u16* gB1 = Bw + (size_t)(n0 + (i1 >> 2)) * ldb + (i1 & 3) * 8;

    f32x4 z = {0.f, 0.f, 0.f, 0.f};
    f32x4 acc[8];
    #pragma unroll
    for (int j = 0; j < 8; ++j) acc[j] = z;

    const int NT = K >> 5;

    auto stage = [&](int buf, int k0) {
        glds16(gA + k0, &As[buf][tid * 8]);
        glds16(gB0 + k0, &Bs[buf][tid * 8]);
        glds16(gB1 + k0, &Bs[buf][i1 * 8]);
    };
    auto compute = [&](int buf) {
        bf16x8 af = ld8(&As[buf][(wave * 16 + lrow) * 32 + lquad * 8]);
        #pragma unroll
        for (int j = 0; j < 8; ++j) {
            bf16x8 bfr = ld8(&Bs[buf][(j * 16 + lrow) * 32 + lquad * 8]);
            acc[j] = __builtin_amdgcn_mfma_f32_16x16x32_bf16(af, bfr, acc[j], 0, 0, 0);
        }
    };

    stage(0, 0);
    __syncthreads();
    for (int kt = 1; kt < NT; ++kt) {
        stage(kt & 1, kt * 32);
        compute((kt - 1) & 1);
        __syncthreads();
    }
    compute((NT - 1) & 1);

    #pragma unroll
    for (int j = 0; j < 8; ++j) {
        int col = n0 + j * 16 + lrow;
        float bv = bias ? bias[col] : 0.f;
        #pragma unroll
        for (int r = 0; r < 4; ++r) {
            int row = m0 + wave * 16 + lquad * 4 + r;
            float v = acc[j][r] + bv;
            if (addres) v += addres[(size_t)row * ldc + col];
            if (outF) outF[(size_t)row * ldc + col] = v;
            else      outH[(size_t)row * ldc + col] = f2bf(v);
        }
    }
}

// variant: B operand f32 (converted during staging); out bf16
__device__ __forceinline__ void gemm64x128_bf32(
    const u16* __restrict__ A, int lda,
    const float* __restrict__ Bf, int ldb,
    u16* __restrict__ outH, int ldc,
    int K, int m0, int n0)
{
    __shared__ u16 As[2][64 * 32];
    __shared__ u16 Bs[2][128 * 32];
    const int tid = threadIdx.x;
    const int lane = tid & 63, wave = tid >> 6;
    const int lrow = lane & 15, lquad = lane >> 4;

    const u16* gA = A + (size_t)(m0 + (tid >> 2)) * lda + (tid & 3) * 8;

    f32x4 z = {0.f, 0.f, 0.f, 0.f};
    f32x4 acc[8];
    #pragma unroll
    for (int j = 0; j < 8; ++j) acc[j] = z;

    const int NT = K >> 5;

    auto stage = [&](int buf, int k0) {
        glds16(gA + k0, &As[buf][tid * 8]);
        #pragma unroll
        for (int it = 0; it < 4; ++it) {
            int idx = tid + 256 * it;          // 1024 float4 segs
            int row = idx >> 3, seg = idx & 7;
            float4 v = *reinterpret_cast<const float4*>(
                Bf + (size_t)(n0 + row) * ldb + k0 + seg * 4);
            u16x4 o;
            o[0] = f2bf(v.x); o[1] = f2bf(v.y); o[2] = f2bf(v.z); o[3] = f2bf(v.w);
            *reinterpret_cast<u16x4*>(&Bs[buf][row * 32 + seg * 4]) = o;
        }
    };
    auto compute = [&](int buf) {
        bf16x8 af = ld8(&As[buf][(wave * 16 + lrow) * 32 + lquad * 8]);
        #pragma unroll
        for (int j = 0; j < 8; ++j) {
            bf16x8 bfr = ld8(&Bs[buf][(j * 16 + lrow) * 32 + lquad * 8]);
            acc[j] = __builtin_amdgcn_mfma_f32_16x16x32_bf16(af, bfr, acc[j], 0, 0, 0);
        }
    };

    stage(0, 0);
    __syncthreads();
    for (int kt = 1; kt < NT; ++kt) {
        stage(kt & 1, kt * 32);
        compute((kt - 1) & 1);
        __syncthreads();
    }
    compute((NT - 1) & 1);

    #pragma unroll
    for (int j = 0; j < 8; ++j) {
        int col = n0 + j * 16 + lrow;
        #pragma unroll
        for (int r = 0; r < 4; ++r) {
            int row = m0 + wave * 16 + lquad * 4 + r;
            outH[(size_t)row * ldc + col] = f2bf(acc[j][r]);
        }
    }
}

// ---------------- GEMM wrapper kernels ----------------

// activation GEMM, M = 8*768.  grid (96, 6).
__global__ __launch_bounds__(256) void k_gemm_act(
    const u16* __restrict__ A, const u16* __restrict__ W5,
    const float* __restrict__ bias5, const int* __restrict__ lang,
    u16* __restrict__ out)
{
    int b = blockIdx.x / 12;
    int l = lang ? lang[b] : 0;
    gemm64x128(A, Hn, W5 + (size_t)l * Hn * Hn, Hn,
               bias5 + (size_t)l * Hn, nullptr, out, nullptr, Hn, Hn,
               blockIdx.x * 64, blockIdx.y * 128);
}

// weight combine: out_z = NT(Afix, B + z*HH).  grid (12,6,5)
__global__ __launch_bounds__(256) void k_comb(
    const u16* __restrict__ Afix, const u16* __restrict__ B5,
    u16* __restrict__ out5)
{
    size_t off = (size_t)blockIdx.z * Hn * Hn;
    gemm64x128(Afix, Hn, B5 + off, Hn, nullptr, nullptr,
               out5 + off, nullptr, Hn, Hn,
               blockIdx.x * 64, blockIdx.y * 128);
}

// Y build: Y_z = NT(MT + z*HH, opwT).  grid (12,6,5)
__global__ __launch_bounds__(256) void k_ybuild(
    const u16* __restrict__ MT5, const u16* __restrict__ Bfix,
    u16* __restrict__ out5)
{
    size_t off = (size_t)blockIdx.z * Hn * Hn;
    gemm64x128(MT5 + off, Hn, Bfix, Hn, nullptr, nullptr,
               out5 + off, nullptr, Hn, Hn,
               blockIdx.x * 64, blockIdx.y * 128);
}

// final: x = NT(z, pjw) + projb + hidden(f32) -> f32 d_out.  grid (96,6)
__global__ __launch_bounds__(256) void k_xgemm(
    const u16* __restrict__ A, const u16* __restrict__ W,
    const float* __restrict__ bias, const float* __restrict__ hidden,
    float* __restrict__ x)
{
    gemm64x128(A, Hn, W, Hn, bias, hidden, nullptr, x, Hn, Hn,
               blockIdx.x * 64, blockIdx.y * 128);
}

// chain step: Pout_l = Pin_l @ F_j^T.  grid (12,6,5)
__global__ __launch_bounds__(256) void k_chain(
    const u16* __restrict__ Pin, u16* __restrict__ Pout,
    const float* __restrict__ align, const int* __restrict__ lang, int j)
{
    int l = blockIdx.z;
    int lj = lang[j];
    const u16* Pl = Pin + (size_t)l * Hn * Hn;
    u16* Po = Pout + (size_t)l * Hn * Hn;
    int m0 = blockIdx.x * 64, n0 = blockIdx.y * 128;
    if (lj == l) {
        int tid = threadIdx.x;
        #pragma unroll
        for (int it = 0; it < 4; ++it) {
            int s = tid + 256 * it;            // 1024 segs of 8 elems
            int row = s >> 4, seg = s & 15;
            *reinterpret_cast<s16x8*>(Po + (size_t)(m0 + row) * Hn + n0 + seg * 8) =
                *reinterpret_cast<const s16x8*>(Pl + (size_t)(m0 + row) * Hn + n0 + seg * 8);
        }
    } else {
        const float* F = align + ((size_t)l * NLn + lj) * Hn * Hn;
        gemm64x128_bf32(Pl, Hn, F, Hn, Po, Hn, Hn, m0, n0);
    }
}

// identity init of MT (5 copies of I).  grid 11520, block 256
__global__ __launch_bounds__(256) void k_init_identity(u16* __restrict__ MT)
{
    size_t idx = (size_t)blockIdx.x * 256 + threadIdx.x;
    int row = (int)((idx / Hn) % Hn);
    int col = (int)(idx % Hn);
    MT[idx] = (row == col) ? (u16)0x3F80 : (u16)0;
}

// combined QK biases.  grid (3, 10), block 256
__global__ __launch_bounds__(256) void k_biasqk(
    const float* __restrict__ ipw, const float* __restrict__ ipb,
    const float* __restrict__ bq_lang, const float* __restrict__ bk_lang,
    float* __restrict__ beff)
{
    int o = blockIdx.x * 256 + threadIdx.x;
    int which = blockIdx.y / 5, l = blockIdx.y % 5;
    const float* w = ipw + (size_t)which * Hn * Hn + (size_t)o * Hn;
    const float* bv = (which ? bk_lang : bq_lang) + (size_t)l * Hn;
    float s = 0.f;
    for (int j = 0; j < Hn; ++j) s += w[j] * bv[j];
    s += ipb[which * Hn + o];
    beff[(size_t)(which * 5 + l) * Hn + o] = s;
}

// opb_eff[l*H + n] = sum_k opb[k] * MT_l[n,k].  grid (3,5), block 256
__global__ __launch_bounds__(256) void k_opbeff(
    const float* __restrict__ opb, const u16* __restrict__ MT5,
    float* __restrict__ out)
{
    int n = blockIdx.x * 256 + threadIdx.x;
    int l = blockIdx.y;
    const u16* mt = MT5 + ((size_t)l * Hn + n) * Hn;
    float s = 0.f;
    for (int k = 0; k < Hn; ++k) s += opb[k] * bf2f(mt[k]);
    out[(size_t)l * Hn + n] = s;
}

// ---------------- flash attention ----------------
// one block per (b, h, 64-query tile); online softmax; dbuf K/V tiles.
// grid (12, NH, B), block 256.
__global__ __launch_bounds__(256) void k_attn(
    const u16* __restrict__ Q, const u16* __restrict__ K,
    const u16* __restrict__ V, u16* __restrict__ ctx)
{
    __shared__ u16 Ks[2][64 * 64];       // [key][d], seg-xor-swizzled
    __shared__ u16 Vt[2][64 * 72];       // [d][key], padded
    __shared__ u16 Pw[4][16 * 68];       // per-wave P, padded

    const int bz = blockIdx.z, h = blockIdx.y, q0 = blockIdx.x * 64;
    const int tid = threadIdx.x;
    const int wave = tid >> 6, lane = tid & 63;
    const int lrow = lane & 15, lquad = lane >> 4;
    const int sw = lrow & 7;             // xor-swizzle key

    const u16* Qp = Q + ((size_t)(bz * Sn + q0 + wave * 16 + lrow)) * Hn + h * HDn;
    const u16* Kb = K + (size_t)bz * Sn * Hn + h * HDn;
    const u16* Vb = V + (size_t)bz * Sn * Hn + h * HDn;

    bf16x8 qa0 = ld8(Qp + lquad * 8);
    bf16x8 qa1 = ld8(Qp + 32 + lquad * 8);

    f32x4 z4 = {0.f, 0.f, 0.f, 0.f};
    float m_r[4], l_r[4];
    f32x4 oacc[4];
    #pragma unroll
    for (int r = 0; r < 4; ++r) { m_r[r] = -1e30f; l_r[r] = 0.f; }
    #pragma unroll
    for (int jd = 0; jd < 4; ++jd) oacc[jd] = z4;

    auto stage = [&](int t0, int buf) {
        #pragma unroll
        for (int it = 0; it < 2; ++it) {
            int idx = tid + 256 * it;          // 512 16B segs
            int row = idx >> 3, p = idx & 7;
            int lseg = p ^ (row & 7);
            glds16(Kb + (size_t)(t0 + row) * Hn + lseg * 8, &Ks[buf][idx * 8]);
        }
        #pragma unroll
        for (int it = 0; it < 2; ++it) {
            int idx = tid + 256 * it;
            int t = idx & 63, d0 = (idx >> 6) * 8;
            s16x8 v = *reinterpret_cast<const s16x8*>(Vb + (size_t)(t0 + t) * Hn + d0);
            #pragma unroll
            for (int j = 0; j < 8; ++j) Vt[buf][(d0 + j) * 72 + t] = (u16)v[j];
        }
    };

    auto compute = [&](int buf) {
        // QK^T for this wave's 16 q-rows x 64 keys
        f32x4 sc[4];
        #pragma unroll
        for (int j = 0; j < 4; ++j) {
            int kr = j * 16 + lrow;
            int base = kr * 64 + ((lquad ^ sw) * 8);
            f32x4 s = __builtin_amdgcn_mfma_f32_16x16x32_bf16(qa0, ld8(&Ks[buf][base]), z4, 0, 0, 0);
            sc[j] = __builtin_amdgcn_mfma_f32_16x16x32_bf16(qa1, ld8(&Ks[buf][base ^ 32]), s, 0, 0, 0);
        }
        #pragma unroll
        for (int j = 0; j < 4; ++j)
            #pragma unroll
            for (int r = 0; r < 4; ++r) sc[j][r] *= 0.125f;
        // row max (across 16 lanes of this quad-group)
        float tmax[4];
        #pragma unroll
        for (int r = 0; r < 4; ++r)
            tmax[r] = fmaxf(fmaxf(sc[0][r], sc[1][r]), fmaxf(sc[2][r], sc[3][r]));
        #pragma unroll
        for (int off = 1; off < 16; off <<= 1)
            #pragma unroll
            for (int r = 0; r < 4; ++r)
                tmax[r] = fmaxf(tmax[r], __shfl_xor(tmax[r], off));
        float alpha[4], ps[4];
        #pragma unroll
        for (int r = 0; r < 4; ++r) {
            float mn = fmaxf(m_r[r], tmax[r]);
            alpha[r] = __expf(m_r[r] - mn);
            m_r[r] = mn;
            ps[r] = 0.f;
        }
        // P = exp(sc - m), stash bf16 into per-wave LDS
        #pragma unroll
        for (int j = 0; j < 4; ++j)
            #pragma unroll
            for (int r = 0; r < 4; ++r) {
                float p = __expf(sc[j][r] - m_r[r]);
                ps[r] += p;
                Pw[wave][(lquad * 4 + r) * 68 + j * 16 + lrow] = f2bf(p);
            }
        #pragma unroll
        for (int off = 1; off < 16; off <<= 1)
            #pragma unroll
            for (int r = 0; r < 4; ++r)
                ps[r] += __shfl_xor(ps[r], off);
        #pragma unroll
        for (int r = 0; r < 4; ++r) l_r[r] = l_r[r] * alpha[r] + ps[r];
        #pragma unroll
        for (int jd = 0; jd < 4; ++jd)
            #pragma unroll
            for (int r = 0; r < 4; ++r) oacc[jd][r] *= alpha[r];
        // PV
        bf16x8 pa0 = ld8(&Pw[wave][lrow * 68 + lquad * 8]);
        bf16x8 pa1 = ld8(&Pw[wave][lrow * 68 + 32 + lquad * 8]);
        #pragma unroll
        for (int jd = 0; jd < 4; ++jd) {
            bf16x8 vb0 = ld8(&Vt[buf][(jd * 16 + lrow) * 72 + lquad * 8]);
            bf16x8 vb1 = ld8(&Vt[buf][(jd * 16 + lrow) * 72 + 32 + lquad * 8]);
            oacc[jd] = __builtin_amdgcn_mfma_f32_16x16x32_bf16(pa0, vb0, oacc[jd], 0, 0, 0);
            oacc[jd] = __builtin_amdgcn_mfma_f32_16x16x32_bf16(pa1, vb1, oacc[jd], 0, 0, 0);
        }
    };

    stage(0, 0);
    __syncthreads();
    for (int kt = 1; kt < 12; ++kt) {
        stage(kt * 64, kt & 1);
        compute((kt - 1) & 1);
        __syncthreads();
    }
    compute(1);  // kt=11 -> buf 1

    float rl[4];
    #pragma unroll
    for (int r = 0; r < 4; ++r) rl[r] = 1.f / l_r[r];
    #pragma unroll
    for (int jd = 0; jd < 4; ++jd)
        #pragma unroll
        for (int r = 0; r < 4; ++r) {
            size_t row = (size_t)bz * Sn + q0 + wave * 16 + lquad * 4 + r;
            ctx[row * Hn + h * HDn + jd * 16 + lrow] = f2bf(oacc[jd][r] * rl[r]);
        }
}

// layernorm in-place on f32 d_out.  grid B*S, block 64
__global__ __launch_bounds__(64) void k_ln(
    float* x, const float* __restrict__ g, const float* __restrict__ beta)
{
    size_t row = blockIdx.x;
    float* xr = x + row * Hn;
    int lane = threadIdx.x;
    float v[12];
    float s = 0.f, ss = 0.f;
    #pragma unroll
    for (int i = 0; i < 12; ++i) {
        v[i] = xr[lane + i * 64];
        s += v[i];
        ss += v[i] * v[i];
    }
    #pragma unroll
    for (int off = 1; off < 64; off <<= 1) {
        s  += __shfl_xor(s, off);
        ss += __shfl_xor(ss, off);
    }
    float mu = s * (1.f / Hn);
    float var = ss * (1.f / Hn) - mu * mu;
    float inv = rsqrtf(var + 1e-5f);
    #pragma unroll
    for (int i = 0; i < 12; ++i) {
        int c = lane + i * 64;
        xr[c] = (v[i] - mu) * inv * g[c] + beta[c];
    }
}

// ---------------- launch ----------------
extern "C" void kernel_launch(void* const* d_in, const int* in_sizes, int n_in,
                              void* d_out, int out_size, void* d_ws, size_t ws_size,
                              hipStream_t stream)
{
    (void)in_sizes; (void)n_in; (void)out_size; (void)ws_size;

    const float* hidden  = (const float*)d_in[0];
    const int*   lang    = (const int*)d_in[1];
    const float* Wq_lang = (const float*)d_in[3];
    const float* bq_lang = (const float*)d_in[4];
    const float* Wk_lang = (const float*)d_in[5];
    const float* bk_lang = (const float*)d_in[6];
    const float* ipw     = (const float*)d_in[7];
    const float* ipb     = (const float*)d_in[8];
    const float* opw     = (const float*)d_in[9];
    const float* opb     = (const float*)d_in[10];
    const float* align   = (const float*)d_in[11];
    const float* projw   = (const float*)d_in[12];
    const float* projb   = (const float*)d_in[13];
    const float* ln_g    = (const float*)d_in[14];
    const float* ln_b    = (const float*)d_in[15];
    float* out = (float*)d_out;

    const size_t HH  = (size_t)Hn * Hn;          // 589824
    const size_t BSH = (size_t)Bn * Sn * Hn;     // 4718592
    const size_t LHH = (size_t)NLn * HH;         // 2949120

    u16* rA = (u16*)d_ws;        // hb -> ctx
    u16* rB = rA + BSH;          // Q -> z
    u16* rC = rB + BSH;          // WqT/WkT -> K -> MT ping
    u16* rD = rC + BSH;          // Weffq/Weffk -> V -> MT pong -> Y
    u16* ipwb = rD + BSH;        // wq|wk|wv bf16 (3*HH)
    u16* pjwb = ipwb + 3 * HH;   // HH
    u16* opwT = pjwb + HH;       // HH
    float* beff   = (float*)(opwT + HH);   // 2*5*768 f32
    float* opbeff = beff + 10 * Hn;        // 5*768 f32

    dim3 gw(12, 6, 5), ga(96, 6);

    // conversions
    k_f2b<<<(unsigned)(BSH / 4 + 255) / 256, 256, 0, stream>>>(hidden, rA, (int)(BSH / 4));
    k_f2b<<<(unsigned)(3 * HH / 4 + 255) / 256, 256, 0, stream>>>(ipw, ipwb, (int)(3 * HH / 4));
    k_f2b<<<(unsigned)(HH / 4 + 255) / 256, 256, 0, stream>>>(projw, pjwb, (int)(HH / 4));
    k_transpose<<<dim3(12, 12, 1), 256, 0, stream>>>(opw, opwT);
    k_biasqk<<<dim3(3, 10), 256, 0, stream>>>(ipw, ipb, bq_lang, bk_lang, beff);

    // Weffq = wq @ Wq[l]  (WqT staged in rC, result in rD)
    k_transpose<<<dim3(12, 12, NLn), 256, 0, stream>>>(Wq_lang, rC);
    k_comb<<<gw, 256, 0, stream>>>(ipwb, rC, rD);
    // Q = hb @ Weffq^T + beffq  -> rB
    k_gemm_act<<<ga, 256, 0, stream>>>(rA, rD, beff, lang, rB);
    // WkT into rC, Weffk -> rD
    k_transpose<<<dim3(12, 12, NLn), 256, 0, stream>>>(Wk_lang, rC);
    k_comb<<<gw, 256, 0, stream>>>(ipwb + HH, rC, rD);
    // K -> rC
    k_gemm_act<<<ga, 256, 0, stream>>>(rA, rD, beff + 5 * Hn, lang, rC);
    // V -> rD
    k_gemm_act<<<ga, 256, 0, stream>>>(rA, ipwb + 2 * HH, ipb + 2 * Hn, nullptr, rD);

    // attention: ctx -> rA (hb dead)
    k_attn<<<dim3(12, NHn, Bn), 256, 0, stream>>>(rB, rC, rD, rA);

    // language chain in rC/rD (K,V dead)
    k_init_identity<<<(unsigned)(LHH / 256), 256, 0, stream>>>(rC);
    u16* Pin = rC;
    u16* Pout = rD;
    for (int j = Bn - 1; j >= 0; --j) {
        k_chain<<<gw, 256, 0, stream>>>(Pin, Pout, align, lang, j);
        u16* t = Pin; Pin = Pout; Pout = t;
    }
    // 8 steps -> MT final back in rC

    k_opbeff<<<dim3(3, NLn), 256, 0, stream>>>(opb, Pin, opbeff);
    // Y_l = MT_l @ opw -> rD
    k_ybuild<<<gw, 256, 0, stream>>>(Pin, opwT, rD);

    // z = ctx @ Y[lang]^T + opb_eff -> rB
    k_gemm_act<<<ga, 256, 0, stream>>>(rA, rD, opbeff, lang, rB);
    // x = z @ projw^T + projb + hidden -> d_out (f32)
    k_xgemm<<<ga, 256, 0, stream>>>(rB, pjwb, projb, hidden, out);
    // layernorm in place
    k_ln<<<(unsigned)(Bn * Sn), 64, 0, stream>>>(out, ln_g, ln_b);
}

// Round 7
// 728.041 us; speedup vs baseline: 1.2254x; 1.2254x over previous
//
#include <hip/hip_runtime.h>

// ---------------- constants ----------------
#define Bn 8
#define Sn 768
#define Hn 768
#define NHn 12
#define HDn 64
#define NLn 5

typedef unsigned short u16;
typedef __bf16 bf16x8 __attribute__((ext_vector_type(8)));
typedef short s16x8 __attribute__((ext_vector_type(8)));
typedef float f32x4 __attribute__((ext_vector_type(4)));
typedef unsigned short u16x4 __attribute__((ext_vector_type(4)));

static __device__ __forceinline__ float bf2f(u16 v) {
    return __uint_as_float(((unsigned)v) << 16);
}
static __device__ __forceinline__ u16 f2bf(float f) {
    unsigned u = __float_as_uint(f);
    unsigned r = u + 0x7fffu + ((u >> 16) & 1u);
    return (u16)(r >> 16);
}
static __device__ __forceinline__ bf16x8 ld8(const u16* p) {
    return *reinterpret_cast<const bf16x8*>(p);
}
static __device__ __forceinline__ void glds16(const u16* g, u16* l) {
    __builtin_amdgcn_global_load_lds(
        (const __attribute__((address_space(1))) void*)g,
        (__attribute__((address_space(3))) void*)l, 16, 0, 0);
}

// ---------------- merged f32 -> bf16 conversion (3 tensors) ----------------
__global__ __launch_bounds__(256) void k_f2b3(
    const float* __restrict__ s0, u16* __restrict__ d0, int n0,
    const float* __restrict__ s1, u16* __restrict__ d1, int n1,
    const float* __restrict__ s2, u16* __restrict__ d2, int n2)
{
    int i = blockIdx.x * 256 + threadIdx.x;
    const float* s; u16* d; int off;
    if (i < n0)           { s = s0; d = d0; off = i; }
    else if (i < n0 + n1) { s = s1; d = d1; off = i - n0; }
    else if (i < n0 + n1 + n2) { s = s2; d = d2; off = i - n0 - n1; }
    else return;
    float4 v = reinterpret_cast<const float4*>(s)[off];
    u16x4 o;
    o[0] = f2bf(v.x); o[1] = f2bf(v.y); o[2] = f2bf(v.z); o[3] = f2bf(v.w);
    reinterpret_cast<u16x4*>(d)[off] = o;
}

// transpose f32 HxH -> bf16 HxH (out[i,o] = in[o,i]).  grid (12,12,count)
__global__ __launch_bounds__(256) void k_transpose(
    const float* __restrict__ in, u16* __restrict__ out)
{
    __shared__ float T[64][65];
    const float* src = in + (size_t)blockIdx.z * Hn * Hn;
    u16* dst = out + (size_t)blockIdx.z * Hn * Hn;
    int i0 = blockIdx.x * 64, o0 = blockIdx.y * 64;
    int x = threadIdx.x & 63, ys = threadIdx.x >> 6;
    for (int r = ys; r < 64; r += 4)
        T[r][x] = src[(size_t)(o0 + r) * Hn + i0 + x];
    __syncthreads();
    for (int r = ys; r < 64; r += 4)
        dst[(size_t)(i0 + r) * Hn + o0 + x] = f2bf(T[x][r]);
}

// ------- 128x128 double-buffered NT GEMM core (256 thr, 4 waves) ---------
// C[m,n] = sum_k A[m,k]*B[n,k]; out bf16 / f32(+addres) / VT-layout.
__device__ __forceinline__ void gemm128(
    const u16* __restrict__ A, int lda,
    const u16* __restrict__ Bw, int ldb,
    const float* __restrict__ bias,
    const float* __restrict__ addres,
    u16* __restrict__ outH, float* __restrict__ outF,
    u16* __restrict__ outVT, int ldc,
    int K, int m0, int n0)
{
    __shared__ u16 As[2][128 * 32];
    __shared__ u16 Bs[2][128 * 32];
    const int tid = threadIdx.x;
    const int lane = tid & 63, wave = tid >> 6;
    const int lrow = lane & 15, lquad = lane >> 4;
    const int wm = (wave >> 1) * 64, wn = (wave & 1) * 64;

    const int s0 = tid, s1 = tid + 256;
    const u16* gA0 = A + (size_t)(m0 + (s0 >> 2)) * lda + (s0 & 3) * 8;
    const u16* gA1 = A + (size_t)(m0 + (s1 >> 2)) * lda + (s1 & 3) * 8;
    const u16* gB0 = Bw + (size_t)(n0 + (s0 >> 2)) * ldb + (s0 & 3) * 8;
    const u16* gB1 = Bw + (size_t)(n0 + (s1 >> 2)) * ldb + (s1 & 3) * 8;

    f32x4 z = {0.f, 0.f, 0.f, 0.f};
    f32x4 acc[4][4];
    #pragma unroll
    for (int i = 0; i < 4; ++i)
        #pragma unroll
        for (int j = 0; j < 4; ++j) acc[i][j] = z;

    const int NT = K >> 5;
    auto stage = [&](int buf, int k0) {
        glds16(gA0 + k0, &As[buf][s0 * 8]);
        glds16(gA1 + k0, &As[buf][s1 * 8]);
        glds16(gB0 + k0, &Bs[buf][s0 * 8]);
        glds16(gB1 + k0, &Bs[buf][s1 * 8]);
    };
    auto compute = [&](int buf) {
        bf16x8 af[4], bf_[4];
        #pragma unroll
        for (int i = 0; i < 4; ++i)
            af[i] = ld8(&As[buf][(wm + i * 16 + lrow) * 32 + lquad * 8]);
        #pragma unroll
        for (int j = 0; j < 4; ++j)
            bf_[j] = ld8(&Bs[buf][(wn + j * 16 + lrow) * 32 + lquad * 8]);
        #pragma unroll
        for (int i = 0; i < 4; ++i)
            #pragma unroll
            for (int j = 0; j < 4; ++j)
                acc[i][j] = __builtin_amdgcn_mfma_f32_16x16x32_bf16(af[i], bf_[j], acc[i][j], 0, 0, 0);
    };

    stage(0, 0);
    __syncthreads();
    for (int kt = 1; kt < NT; ++kt) {
        stage(kt & 1, kt * 32);
        compute((kt - 1) & 1);
        __syncthreads();
    }
    compute((NT - 1) & 1);

    #pragma unroll
    for (int i = 0; i < 4; ++i) {
        #pragma unroll
        for (int j = 0; j < 4; ++j) {
            int col = n0 + wn + j * 16 + lrow;
            float bv = bias ? bias[col] : 0.f;
            if (outVT) {
                // V^T layout: [b][h][d][s], 4 consecutive s per lane
                int row0 = m0 + wm + i * 16 + lquad * 4;
                int bb = row0 / Sn, s = row0 % Sn;
                int hh = col >> 6, dd = col & 63;
                u16x4 o;
                #pragma unroll
                for (int r = 0; r < 4; ++r) o[r] = f2bf(acc[i][j][r] + bv);
                *reinterpret_cast<u16x4*>(
                    outVT + (((size_t)bb * NHn + hh) * 64 + dd) * Sn + s) = o;
            } else {
                #pragma unroll
                for (int r = 0; r < 4; ++r) {
                    int row = m0 + wm + i * 16 + lquad * 4 + r;
                    float v = acc[i][j][r] + bv;
                    if (addres) v += addres[(size_t)row * ldc + col];
                    if (outF) outF[(size_t)row * ldc + col] = v;
                    else      outH[(size_t)row * ldc + col] = f2bf(v);
                }
            }
        }
    }
}

// single-buffered variant: B operand f32 (converted during staging); out bf16
__device__ __forceinline__ void gemm128_bf32(
    const u16* __restrict__ A, int lda,
    const float* __restrict__ Bf, int ldb,
    u16* __restrict__ outH, int ldc,
    int K, int m0, int n0)
{
    __shared__ u16 As[128 * 32];
    __shared__ u16 Bs[128 * 32];
    const int tid = threadIdx.x;
    const int lane = tid & 63, wave = tid >> 6;
    const int lrow = lane & 15, lquad = lane >> 4;
    const int wm = (wave >> 1) * 64, wn = (wave & 1) * 64;

    const int s0 = tid, s1 = tid + 256;
    const u16* gA0 = A + (size_t)(m0 + (s0 >> 2)) * lda + (s0 & 3) * 8;
    const u16* gA1 = A + (size_t)(m0 + (s1 >> 2)) * lda + (s1 & 3) * 8;

    f32x4 z = {0.f, 0.f, 0.f, 0.f};
    f32x4 acc[4][4];
    #pragma unroll
    for (int i = 0; i < 4; ++i)
        #pragma unroll
        for (int j = 0; j < 4; ++j) acc[i][j] = z;

    for (int k0 = 0; k0 < K; k0 += 32) {
        glds16(gA0 + k0, &As[s0 * 8]);
        glds16(gA1 + k0, &As[s1 * 8]);
        #pragma unroll
        for (int it = 0; it < 4; ++it) {
            int idx = tid + 256 * it;
            int row = idx >> 3, seg = idx & 7;
            float4 v = *reinterpret_cast<const float4*>(
                Bf + (size_t)(n0 + row) * ldb + k0 + seg * 4);
            u16x4 o;
            o[0] = f2bf(v.x); o[1] = f2bf(v.y); o[2] = f2bf(v.z); o[3] = f2bf(v.w);
            *reinterpret_cast<u16x4*>(&Bs[row * 32 + seg * 4]) = o;
        }
        __syncthreads();
        bf16x8 af[4], bf_[4];
        #pragma unroll
        for (int i = 0; i < 4; ++i)
            af[i] = ld8(&As[(wm + i * 16 + lrow) * 32 + lquad * 8]);
        #pragma unroll
        for (int j = 0; j < 4; ++j)
            bf_[j] = ld8(&Bs[(wn + j * 16 + lrow) * 32 + lquad * 8]);
        #pragma unroll
        for (int i = 0; i < 4; ++i)
            #pragma unroll
            for (int j = 0; j < 4; ++j)
                acc[i][j] = __builtin_amdgcn_mfma_f32_16x16x32_bf16(af[i], bf_[j], acc[i][j], 0, 0, 0);
        __syncthreads();
    }

    #pragma unroll
    for (int i = 0; i < 4; ++i)
        #pragma unroll
        for (int j = 0; j < 4; ++j) {
            int col = n0 + wn + j * 16 + lrow;
            #pragma unroll
            for (int r = 0; r < 4; ++r) {
                int row = m0 + wm + i * 16 + lquad * 4 + r;
                outH[(size_t)row * ldc + col] = f2bf(acc[i][j][r]);
            }
        }
}

// ---------------- GEMM wrapper kernels ----------------

// activation GEMM, M = 8*768.  grid (48, 6).
__global__ __launch_bounds__(256) void k_gemm_act(
    const u16* __restrict__ A, const u16* __restrict__ W5,
    const float* __restrict__ bias5, const int* __restrict__ lang,
    u16* __restrict__ out)
{
    int b = blockIdx.x / 6;
    int l = lang ? lang[b] : 0;
    gemm128(A, Hn, W5 + (size_t)l * Hn * Hn, Hn,
            bias5 + (size_t)l * Hn, nullptr, out, nullptr, nullptr, Hn, Hn,
            blockIdx.x * 128, blockIdx.y * 128);
}

// V projection writing V^T layout.  grid (48, 6).
__global__ __launch_bounds__(256) void k_gemm_vt(
    const u16* __restrict__ A, const u16* __restrict__ W,
    const float* __restrict__ bias, u16* __restrict__ outVT)
{
    gemm128(A, Hn, W, Hn, bias, nullptr, nullptr, nullptr, outVT, Hn, Hn,
            blockIdx.x * 128, blockIdx.y * 128);
}

// weight combine: out_z = NT(Afix, B + z*HH).  grid (6,6,5)
__global__ __launch_bounds__(256) void k_comb(
    const u16* __restrict__ Afix, const u16* __restrict__ B5,
    u16* __restrict__ out5)
{
    size_t off = (size_t)blockIdx.z * Hn * Hn;
    gemm128(Afix, Hn, B5 + off, Hn, nullptr, nullptr,
            out5 + off, nullptr, nullptr, Hn, Hn,
            blockIdx.x * 128, blockIdx.y * 128);
}

// Y build: Y_z = NT(MT + z*HH, opwT).  grid (6,6,5)
__global__ __launch_bounds__(256) void k_ybuild(
    const u16* __restrict__ MT5, const u16* __restrict__ Bfix,
    u16* __restrict__ out5)
{
    size_t off = (size_t)blockIdx.z * Hn * Hn;
    gemm128(MT5 + off, Hn, Bfix, Hn, nullptr, nullptr,
            out5 + off, nullptr, nullptr, Hn, Hn,
            blockIdx.x * 128, blockIdx.y * 128);
}

// final: x = NT(z, pjw) + projb + hidden(f32) -> f32 d_out.  grid (48,6)
__global__ __launch_bounds__(256) void k_xgemm(
    const u16* __restrict__ A, const u16* __restrict__ W,
    const float* __restrict__ bias, const float* __restrict__ hidden,
    float* __restrict__ x)
{
    gemm128(A, Hn, W, Hn, bias, hidden, nullptr, x, nullptr, Hn, Hn,
            blockIdx.x * 128, blockIdx.y * 128);
}

// chain step: Pout_l = Pin_l @ F_j^T.  grid (6,6,5)
__global__ __launch_bounds__(256) void k_chain(
    const u16* __restrict__ Pin, u16* __restrict__ Pout,
    const float* __restrict__ align, const int* __restrict__ lang, int j)
{
    int l = blockIdx.z;
    int lj = lang[j];
    const u16* Pl = Pin + (size_t)l * Hn * Hn;
    u16* Po = Pout + (size_t)l * Hn * Hn;
    int m0 = blockIdx.x * 128, n0 = blockIdx.y * 128;
    if (lj == l) {
        int tid = threadIdx.x;
        #pragma unroll
        for (int it = 0; it < 8; ++it) {
            int s = tid + 256 * it;            // 2048 segs of 8 elems
            int row = s >> 4, seg = s & 15;
            *reinterpret_cast<s16x8*>(Po + (size_t)(m0 + row) * Hn + n0 + seg * 8) =
                *reinterpret_cast<const s16x8*>(Pl + (size_t)(m0 + row) * Hn + n0 + seg * 8);
        }
    } else {
        const float* F = align + ((size_t)l * NLn + lj) * Hn * Hn;
        gemm128_bf32(Pl, Hn, F, Hn, Po, Hn, Hn, m0, n0);
    }
}

// identity init of MT (5 copies of I).  grid 11520, block 256
__global__ __launch_bounds__(256) void k_init_identity(u16* __restrict__ MT)
{
    size_t idx = (size_t)blockIdx.x * 256 + threadIdx.x;
    int row = (int)((idx / Hn) % Hn);
    int col = (int)(idx % Hn);
    MT[idx] = (row == col) ? (u16)0x3F80 : (u16)0;
}

// combined QK biases.  grid (3, 10), block 256
__global__ __launch_bounds__(256) void k_biasqk(
    const float* __restrict__ ipw, const float* __restrict__ ipb,
    const float* __restrict__ bq_lang, const float* __restrict__ bk_lang,
    float* __restrict__ beff)
{
    int o = blockIdx.x * 256 + threadIdx.x;
    int which = blockIdx.y / 5, l = blockIdx.y % 5;
    const float* w = ipw + (size_t)which * Hn * Hn + (size_t)o * Hn;
    const float* bv = (which ? bk_lang : bq_lang) + (size_t)l * Hn;
    float s = 0.f;
    for (int j = 0; j < Hn; ++j) s += w[j] * bv[j];
    s += ipb[which * Hn + o];
    beff[(size_t)(which * 5 + l) * Hn + o] = s;
}

// opb_eff[l*H + n] = sum_k opb[k] * MT_l[n,k].  grid (3,5), block 256
__global__ __launch_bounds__(256) void k_opbeff(
    const float* __restrict__ opb, const u16* __restrict__ MT5,
    float* __restrict__ out)
{
    int n = blockIdx.x * 256 + threadIdx.x;
    int l = blockIdx.y;
    const u16* mt = MT5 + ((size_t)l * Hn + n) * Hn;
    float s = 0.f;
    for (int k = 0; k < Hn; ++k) s += opb[k] * bf2f(mt[k]);
    out[(size_t)l * Hn + n] = s;
}

// ---------------- flash attention (V^T input) ----------------
// one block per (b, h, 64-query tile); online softmax; dbuf K/V^T via glds16.
// grid (12, NH, B), block 256.
__global__ __launch_bounds__(256) void k_attn(
    const u16* __restrict__ Q, const u16* __restrict__ K,
    const u16* __restrict__ VT, u16* __restrict__ ctx)
{
    __shared__ u16 Ks[2][64 * 64];       // [key][d], seg-xor-swizzled
    __shared__ u16 Vs[2][64 * 64];       // [d][key], seg-xor-swizzled
    __shared__ u16 Pw[4][16 * 72];       // per-wave P, 16B-aligned stride

    const int bz = blockIdx.z, h = blockIdx.y, q0 = blockIdx.x * 64;
    const int tid = threadIdx.x;
    const int wave = tid >> 6, lane = tid & 63;
    const int lrow = lane & 15, lquad = lane >> 4;
    const int sw = lrow & 7;

    const u16* Qp = Q + ((size_t)(bz * Sn + q0 + wave * 16 + lrow)) * Hn + h * HDn;
    const u16* Kb = K + (size_t)bz * Sn * Hn + h * HDn;
    const u16* Vb = VT + ((size_t)(bz * NHn + h) * 64) * Sn;   // row d, stride Sn

    bf16x8 qa0 = ld8(Qp + lquad * 8);
    bf16x8 qa1 = ld8(Qp + 32 + lquad * 8);

    f32x4 z4 = {0.f, 0.f, 0.f, 0.f};
    float m_r[4], l_r[4];
    f32x4 oacc[4];
    #pragma unroll
    for (int r = 0; r < 4; ++r) { m_r[r] = -1e30f; l_r[r] = 0.f; }
    #pragma unroll
    for (int jd = 0; jd < 4; ++jd) oacc[jd] = z4;

    auto stage = [&](int t0, int buf) {
        #pragma unroll
        for (int it = 0; it < 2; ++it) {
            int idx = tid + 256 * it;          // 512 16B segs
            int row = idx >> 3, p = idx & 7;
            glds16(Kb + (size_t)(t0 + row) * Hn + (p ^ (row & 7)) * 8,
                   &Ks[buf][idx * 8]);
        }
        #pragma unroll
        for (int it = 0; it < 2; ++it) {
            int idx = tid + 256 * it;
            int d = idx >> 3, p = idx & 7;
            glds16(Vb + (size_t)d * Sn + t0 + (p ^ (d & 7)) * 8,
                   &Vs[buf][idx * 8]);
        }
    };

    auto compute = [&](int buf) {
        // QK^T: this wave's 16 q-rows x 64 keys
        f32x4 sc[4];
        #pragma unroll
        for (int j = 0; j < 4; ++j) {
            int base = (j * 16 + lrow) * 64 + ((lquad ^ sw) * 8);
            f32x4 s = __builtin_amdgcn_mfma_f32_16x16x32_bf16(qa0, ld8(&Ks[buf][base]), z4, 0, 0, 0);
            sc[j] = __builtin_amdgcn_mfma_f32_16x16x32_bf16(qa1, ld8(&Ks[buf][base ^ 32]), s, 0, 0, 0);
        }
        #pragma unroll
        for (int j = 0; j < 4; ++j)
            #pragma unroll
            for (int r = 0; r < 4; ++r) sc[j][r] *= 0.125f;
        float tmax[4];
        #pragma unroll
        for (int r = 0; r < 4; ++r)
            tmax[r] = fmaxf(fmaxf(sc[0][r], sc[1][r]), fmaxf(sc[2][r], sc[3][r]));
        #pragma unroll
        for (int off = 1; off < 16; off <<= 1)
            #pragma unroll
            for (int r = 0; r < 4; ++r)
                tmax[r] = fmaxf(tmax[r], __shfl_xor(tmax[r], off));
        float alpha[4], ps[4];
        #pragma unroll
        for (int r = 0; r < 4; ++r) {
            float mn = fmaxf(m_r[r], tmax[r]);
            alpha[r] = __expf(m_r[r] - mn);
            m_r[r] = mn;
            ps[r] = 0.f;
        }
        #pragma unroll
        for (int j = 0; j < 4; ++j)
            #pragma unroll
            for (int r = 0; r < 4; ++r) {
                float p = __expf(sc[j][r] - m_r[r]);
                ps[r] += p;
                Pw[wave][(lquad * 4 + r) * 72 + j * 16 + lrow] = f2bf(p);
            }
        #pragma unroll
        for (int off = 1; off < 16; off <<= 1)
            #pragma unroll
            for (int r = 0; r < 4; ++r)
                ps[r] += __shfl_xor(ps[r], off);
        #pragma unroll
        for (int r = 0; r < 4; ++r) l_r[r] = l_r[r] * alpha[r] + ps[r];
        #pragma unroll
        for (int jd = 0; jd < 4; ++jd)
            #pragma unroll
            for (int r = 0; r < 4; ++r) oacc[jd][r] *= alpha[r];
        // PV: A = P[q][key], B = V^T[d][key]
        bf16x8 pa0 = ld8(&Pw[wave][lrow * 72 + lquad * 8]);
        bf16x8 pa1 = ld8(&Pw[wave][lrow * 72 + 32 + lquad * 8]);
        #pragma unroll
        for (int jd = 0; jd < 4; ++jd) {
            int vbase = (jd * 16 + lrow) * 64 + ((lquad ^ sw) * 8);
            oacc[jd] = __builtin_amdgcn_mfma_f32_16x16x32_bf16(pa0, ld8(&Vs[buf][vbase]), oacc[jd], 0, 0, 0);
            oacc[jd] = __builtin_amdgcn_mfma_f32_16x16x32_bf16(pa1, ld8(&Vs[buf][vbase ^ 32]), oacc[jd], 0, 0, 0);
        }
    };

    stage(0, 0);
    __syncthreads();
    for (int kt = 1; kt < 12; ++kt) {
        stage(kt * 64, kt & 1);
        compute((kt - 1) & 1);
        __syncthreads();
    }
    compute(1);

    float rl[4];
    #pragma unroll
    for (int r = 0; r < 4; ++r) rl[r] = 1.f / l_r[r];
    #pragma unroll
    for (int jd = 0; jd < 4; ++jd)
        #pragma unroll
        for (int r = 0; r < 4; ++r) {
            size_t row = (size_t)bz * Sn + q0 + wave * 16 + lquad * 4 + r;
            ctx[row * Hn + h * HDn + jd * 16 + lrow] = f2bf(oacc[jd][r] * rl[r]);
        }
}

// layernorm in-place on f32 d_out.  grid B*S, block 64
__global__ __launch_bounds__(64) void k_ln(
    float* x, const float* __restrict__ g, const float* __restrict__ beta)
{
    size_t row = blockIdx.x;
    float* xr = x + row * Hn;
    int lane = threadIdx.x;
    float v[12];
    float s = 0.f, ss = 0.f;
    #pragma unroll
    for (int i = 0; i < 12; ++i) {
        v[i] = xr[lane + i * 64];
        s += v[i];
        ss += v[i] * v[i];
    }
    #pragma unroll
    for (int off = 1; off < 64; off <<= 1) {
        s  += __shfl_xor(s, off);
        ss += __shfl_xor(ss, off);
    }
    float mu = s * (1.f / Hn);
    float var = ss * (1.f / Hn) - mu * mu;
    float inv = rsqrtf(var + 1e-5f);
    #pragma unroll
    for (int i = 0; i < 12; ++i) {
        int c = lane + i * 64;
        xr[c] = (v[i] - mu) * inv * g[c] + beta[c];
    }
}

// ---------------- launch ----------------
extern "C" void kernel_launch(void* const* d_in, const int* in_sizes, int n_in,
                              void* d_out, int out_size, void* d_ws, size_t ws_size,
                              hipStream_t stream)
{
    (void)in_sizes; (void)n_in; (void)out_size; (void)ws_size;

    const float* hidden  = (const float*)d_in[0];
    const int*   lang    = (const int*)d_in[1];
    const float* Wq_lang = (const float*)d_in[3];
    const float* bq_lang = (const float*)d_in[4];
    const float* Wk_lang = (const float*)d_in[5];
    const float* bk_lang = (const float*)d_in[6];
    const float* ipw     = (const float*)d_in[7];
    const float* ipb     = (const float*)d_in[8];
    const float* opw     = (const float*)d_in[9];
    const float* opb     = (const float*)d_in[10];
    const float* align   = (const float*)d_in[11];
    const float* projw   = (const float*)d_in[12];
    const float* projb   = (const float*)d_in[13];
    const float* ln_g    = (const float*)d_in[14];
    const float* ln_b    = (const float*)d_in[15];
    float* out = (float*)d_out;

    const size_t HH  = (size_t)Hn * Hn;          // 589824
    const size_t BSH = (size_t)Bn * Sn * Hn;     // 4718592
    const size_t LHH = (size_t)NLn * HH;         // 2949120

    u16* rA = (u16*)d_ws;        // hb -> ctx
    u16* rB = rA + BSH;          // Q -> z
    u16* rC = rB + BSH;          // WqT/WkT -> K -> MT ping
    u16* rD = rC + BSH;          // Weffq/Weffk -> V^T -> MT pong -> Y
    u16* ipwb = rD + BSH;        // wq|wk|wv bf16 (3*HH)
    u16* pjwb = ipwb + 3 * HH;   // HH
    u16* opwT = pjwb + HH;       // HH
    float* beff   = (float*)(opwT + HH);   // 2*5*768 f32
    float* opbeff = beff + 10 * Hn;        // 5*768 f32

    dim3 gw(6, 6, 5), ga(48, 6);

    // conversions (merged) + transposes + bias folds
    {
        int n0 = (int)(BSH / 4), n1 = (int)(3 * HH / 4), n2 = (int)(HH / 4);
        k_f2b3<<<(unsigned)((n0 + n1 + n2 + 255) / 256), 256, 0, stream>>>(
            hidden, rA, n0, ipw, ipwb, n1, projw, pjwb, n2);
    }
    k_transpose<<<dim3(12, 12, 1), 256, 0, stream>>>(opw, opwT);
    k_biasqk<<<dim3(3, 10), 256, 0, stream>>>(ipw, ipb, bq_lang, bk_lang, beff);

    // Weffq = wq @ Wq[l]  (WqT staged in rC, result in rD)
    k_transpose<<<dim3(12, 12, NLn), 256, 0, stream>>>(Wq_lang, rC);
    k_comb<<<gw, 256, 0, stream>>>(ipwb, rC, rD);
    // Q = hb @ Weffq^T + beffq  -> rB
    k_gemm_act<<<ga, 256, 0, stream>>>(rA, rD, beff, lang, rB);
    // WkT into rC, Weffk -> rD
    k_transpose<<<dim3(12, 12, NLn), 256, 0, stream>>>(Wk_lang, rC);
    k_comb<<<gw, 256, 0, stream>>>(ipwb + HH, rC, rD);
    // K -> rC
    k_gemm_act<<<ga, 256, 0, stream>>>(rA, rD, beff + 5 * Hn, lang, rC);
    // V^T -> rD
    k_gemm_vt<<<ga, 256, 0, stream>>>(rA, ipwb + 2 * HH, ipb + 2 * Hn, rD);

    // attention: ctx -> rA (hb dead)
    k_attn<<<dim3(12, NHn, Bn), 256, 0, stream>>>(rB, rC, rD, rA);

    // language chain in rC/rD (K, V^T dead)
    k_init_identity<<<(unsigned)(LHH / 256), 256, 0, stream>>>(rC);
    u16* Pin = rC;
    u16* Pout = rD;
    for (int j = Bn - 1; j >= 0; --j) {
        k_chain<<<gw, 256, 0, stream>>>(Pin, Pout, align, lang, j);
        u16* t = Pin; Pin = Pout; Pout = t;
    }
    // 8 steps -> MT final back in rC

    k_opbeff<<<dim3(3, NLn), 256, 0, stream>>>(opb, Pin, opbeff);
    // Y_l = MT_l @ opw -> rD
    k_ybuild<<<gw, 256, 0, stream>>>(Pin, opwT, rD);

    // z = ctx @ Y[lang]^T + opb_eff -> rB
    k_gemm_act<<<ga, 256, 0, stream>>>(rA, rD, opbeff, lang, rB);
    // x = z @ projw^T + projb + hidden -> d_out (f32)
    k_xgemm<<<ga, 256, 0, stream>>>(rB, pjwb, projb, hidden, out);
    // layernorm in place
    k_ln<<<(unsigned)(Bn * Sn), 64, 0, stream>>>(out, ln_g, ln_b);
}